// Round 7
// baseline (204.287 us; speedup 1.0000x reference)
//
#include <hip/hip_runtime.h>
#include <stdint.h>

typedef int   i32x4 __attribute__((ext_vector_type(4)));
typedef float f32x4 __attribute__((ext_vector_type(4)));

// ---------------- workspace layout (bytes) ----------------
#define WS_PART    0                         // 1536 floats: per-block absmax partials
#define WS_XQ      32768                     // 4 MB  int8 swizzled [32][16][4][128][16]
#define WS_W1QT    (WS_XQ   + 4096*1024)     // 4 MB  w1^T swizzled [32][16][4][128][16]
#define WS_W2QT    (WS_W1QT + 4096*1024)     // 4 MB  w2^T swizzled [8][64][4][128][16]
#define WS_PS      (WS_W2QT + 4096*1024)     // 16 MB plane_s swizzled [32][64][4][128][16]
#define WS_PH      (WS_PS   + 4096*4096)     // 16 MB plane_h

// block-wide absmax over p0[0..n0) and optional p1[0..n1); bit-exact in any order
__device__ __forceinline__ float block_absmax(const float* __restrict__ p0, int n0,
                                              const float* __restrict__ p1, int n1,
                                              float* red, float* slot) {
  int tid = threadIdx.x, nt = blockDim.x;
  float m = 0.f;
  for (int i = tid; i < n0; i += nt) m = fmaxf(m, fabsf(p0[i]));
  if (p1) for (int i = tid; i < n1; i += nt) m = fmaxf(m, fabsf(p1[i]));
  for (int off = 32; off; off >>= 1) m = fmaxf(m, __shfl_down(m, off));
  if ((tid & 63) == 0) red[tid >> 6] = m;
  __syncthreads();
  if (tid == 0) {
    int nw = nt >> 6;
    float M = red[0];
    for (int w = 1; w < nw; w++) M = fmaxf(M, red[w]);
    *slot = M;
  }
  __syncthreads();
  return *slot;
}

// ---------------- abs-max partials over x, w1f, w2f ----------------
__global__ void k_absmax3(const float* __restrict__ x, const float* __restrict__ w1,
                          const float* __restrict__ w2, float* __restrict__ part) {
  int seg = blockIdx.x >> 9;              // 0,1,2
  int b = blockIdx.x & 511;
  const float* p = (seg == 0) ? x : (seg == 1) ? w1 : w2;
  int i = b * 256 + threadIdx.x;
  float m = 0.f;
  #pragma unroll
  for (int it = 0; it < 8; it++) {
    f32x4 v = ((const f32x4*)p)[i + it * 131072];
    m = fmaxf(m, fmaxf(fmaxf(fabsf(v.x), fabsf(v.y)), fmaxf(fabsf(v.z), fabsf(v.w))));
  }
  for (int off = 32; off; off >>= 1) m = fmaxf(m, __shfl_down(m, off));
  __shared__ float red[4];
  if ((threadIdx.x & 63) == 0) red[threadIdx.x >> 6] = m;
  __syncthreads();
  if (threadIdx.x == 0)
    part[blockIdx.x] = fmaxf(fmaxf(red[0], red[1]), fmaxf(red[2], red[3]));
}

// ---------------- quantize + transpose a weight matrix (inline body) ----------------
__device__ __forceinline__ void quantT_body(const float* __restrict__ w, float s,
                                            i32x4* __restrict__ out, int C, int tkbits,
                                            int b) {
  int L = b * 256 + threadIdx.x;
  int h_in = L & 127;
  int kb = (L >> 7) & 3;
  int tk = (L >> 9) & ((1 << tkbits) - 1);
  int hblk = L >> (9 + tkbits);
  int h = hblk * 128 + h_in;
  int k0 = (tk * 4 + kb) * 16;
  int wd[4];
  #pragma unroll
  for (int d = 0; d < 4; d++) {
    unsigned acc = 0;
    #pragma unroll
    for (int j = 0; j < 4; j++) {
      float v = w[(size_t)(k0 + d * 4 + j) * C + h];
      int q = (int)rintf(v / s) & 255;
      acc |= (unsigned)q << (8 * j);
    }
    wd[d] = (int)acc;
  }
  i32x4 o; o.x = wd[0]; o.y = wd[1]; o.z = wd[2]; o.w = wd[3];
  out[L] = o;
}

// ---------------- fused prep: quant_x + quantT(w1) + quantT(w2) ----------------
__global__ void k_prep(const float* __restrict__ x, const float* __restrict__ w1f,
                       const float* __restrict__ w2f, const float* __restrict__ b1f,
                       const float* __restrict__ b2f, const float* __restrict__ part,
                       i32x4* __restrict__ xq, i32x4* __restrict__ w1qt,
                       i32x4* __restrict__ w2qt) {
  __shared__ float red[4];
  __shared__ float slot;
  int seg = blockIdx.x >> 10;             // block-uniform
  int b = blockIdx.x & 1023;
  if (seg == 0) {
    float s = block_absmax(part, 512, nullptr, 0, red, &slot) / 127.0f;
    int L = b * 256 + threadIdx.x;
    int m_in = L & 127, kb = (L >> 7) & 3, tk = (L >> 9) & 15, mblk = L >> 13;
    int m = mblk * 128 + m_in;
    int k0 = (tk * 4 + kb) * 16;
    const f32x4* px = (const f32x4*)(x + m * 1024 + k0);
    int wd[4];
    #pragma unroll
    for (int d = 0; d < 4; d++) {
      f32x4 v = px[d];
      int b0 = (int)rintf(v.x / s) & 255;
      int b1 = (int)rintf(v.y / s) & 255;
      int b2 = (int)rintf(v.z / s) & 255;
      int b3 = (int)rintf(v.w / s) & 255;
      wd[d] = b0 | (b1 << 8) | (b2 << 16) | (b3 << 24);
    }
    i32x4 o; o.x = wd[0]; o.y = wd[1]; o.z = wd[2]; o.w = wd[3];
    xq[L] = o;
  } else if (seg == 1) {
    float s = block_absmax(part + 512, 512, b1f, 4096, red, &slot) / 127.0f;
    quantT_body(w1f, s, w1qt, 4096, 4, b);
  } else {
    float s = block_absmax(part + 1024, 512, b2f, 1024, red, &slot) / 127.0f;
    quantT_body(w2f, s, w2qt, 1024, 6, b);
  }
}

// ---------------- GEMM1: o1^T = w1q^T · x_q^T  (NO LDS staging, NO loop barriers) ----
// All fragments loaded directly global->VGPR from the swizzled layouts
// (16 consecutive i32x4 per 16-lane group = coalesced 256B segments).
// Per-fragment WAR refill right after last use; sibling-wave duplicate reads hit L1.
__launch_bounds__(256, 4)
__global__ void k_gemm1(const i32x4* __restrict__ Aq, const i32x4* __restrict__ Bq,
                        const float* __restrict__ part, const float* __restrict__ b1f,
                        unsigned* __restrict__ plane_s, unsigned* __restrict__ plane_h) {
  __shared__ float red[4];
  __shared__ float slot;
  __shared__ int b1s[128];
  int tid = threadIdx.x;
  int bb = blockIdx.x;   // batch block, 0..31
  int hb = blockIdx.y;   // H block,    0..31
  int lane = tid & 63, wid = tid >> 6;
  int wm = wid & 1, wn = wid >> 1;
  int g = lane >> 4, l15 = lane & 15;

  const i32x4* gA = Aq + (size_t)hb * 16 * 512 + g * 128 + wm * 64 + l15;
  const i32x4* gB = Bq + (size_t)bb * 16 * 512 + g * 128 + wn * 64 + l15;

  // fragment prefetch t=0 (latency overlaps the scale phase)
  i32x4 af[4], bf[4];
  #pragma unroll
  for (int r = 0; r < 4; r++) af[r] = gA[r * 16];
  #pragma unroll
  for (int c = 0; c < 4; c++) bf[c] = gB[c * 16];

  // recompute scales from partials (bit-identical across kernels)
  float sx  = block_absmax(part, 512, nullptr, 0, red, &slot) / 127.0f;
  float s1v = block_absmax(part + 512, 512, b1f, 4096, red, &slot) / 127.0f;
  float mult1 = sx * s1v / s1v;   // exact f32 expr as reference
  if (tid < 128) b1s[tid] = (int)rintf(b1f[hb * 128 + tid] / s1v);
  __syncthreads();               // b1s visible to all (last barrier in kernel body)

  i32x4 acc[4][4];
  #pragma unroll
  for (int r = 0; r < 4; r++)
    #pragma unroll
    for (int c = 0; c < 4; c++) acc[r][c] = (i32x4)(0);

  for (int t = 0; t < 16; ++t) {
    int tn = (t + 1 < 16) ? (t + 1) : 15;         // last iter re-reads (harmless)
    const i32x4* gAn = gA + (size_t)tn * 512;
    const i32x4* gBn = gB + (size_t)tn * 512;
    #pragma unroll
    for (int r = 0; r < 4; r++) {
      #pragma unroll
      for (int c = 0; c < 4; c++)
        acc[r][c] = __builtin_amdgcn_mfma_i32_16x16x64_i8(af[r], bf[c], acc[r][c], 0, 0, 0);
      af[r] = gAn[r * 16];                        // WAR refill after last use of af[r]
    }
    #pragma unroll
    for (int c = 0; c < 4; c++) bf[c] = gBn[c * 16];
  }

  int t2base = hb * 2 + wm;
  #pragma unroll
  for (int r = 0; r < 4; r++) {
    int hloc = wm * 64 + r * 16 + 4 * g;
    int bq0 = b1s[hloc], bq1 = b1s[hloc + 1], bq2 = b1s[hloc + 2], bq3 = b1s[hloc + 3];
    #pragma unroll
    for (int c = 0; c < 4; c++) {
      unsigned lo = 0, hi = 0;
      #pragma unroll
      for (int q = 0; q < 4; q++) {
        int y0 = acc[r][c][q];
        int bqv = (q == 0) ? bq0 : (q == 1) ? bq1 : (q == 2) ? bq2 : bq3;
        int o = (short)((int)rintf((float)y0 * mult1) + bqv);    // int16 semantics
        int a = o > 0 ? o : 0;                                   // relu
        int s8 = (int)(signed char)(a & 0xFF);
        int h8 = (a >> 8) + (s8 < 0 ? 1 : 0);                    // a = 256*h8 + s8
        lo |= (unsigned)(s8 & 0xFF) << (8 * q);
        hi |= (unsigned)(h8 & 0xFF) << (8 * q);
      }
      int m_in = wn * 64 + c * 16 + l15;
      unsigned idx = (((unsigned)(bb * 64 + t2base) * 512u + (unsigned)(r * 128 + m_in)) << 2) + g;
      plane_s[idx] = lo;
      plane_h[idx] = hi;
    }
  }
}

// ---------------- GEMM2: 32x128 tile, split-K, all operands direct-to-reg -----------
// 1024 blocks x 512 thr; waves: kh2 x wm2 x wn2, wave tile = 16 rows x 64 cols,
// acc = 32 regs (dual plane). NO LDS staging, NO barriers in the K-loop —
// double-buffered register prefetch (unroll 2 -> ping-pong). One-time LDS merge.
// Grid map L = nb*128 + mb: all 8 nb-sharers of an mb plane-strip land on one XCD.
__launch_bounds__(512, 4)
__global__ void k_gemm2(const i32x4* __restrict__ Ps, const i32x4* __restrict__ Ph,
                        const i32x4* __restrict__ Bq, const float* __restrict__ part,
                        const float* __restrict__ b1f, const float* __restrict__ b2f,
                        float* __restrict__ out) {
  __shared__ float red[8];
  __shared__ float slot;
  __shared__ int mg[32 * 128];   // 16 KB merge buffer
  int tid = threadIdx.x;
  int L = blockIdx.x;
  int mb = L & 127;              // 32-row strip
  int nb = L >> 7;               // 0..7
  int mblk = mb >> 2;
  int m128 = (mb & 3) * 32;
  int wid = tid >> 6, lane = tid & 63;
  int kh = wid >> 2, w2 = wid & 3;
  int wm = w2 & 1, wn = w2 >> 1;
  int g = lane >> 4, l15 = lane & 15;

  const i32x4* gS = Ps + (((size_t)mblk * 64 + kh * 32) << 9) + g * 128 + m128 + wm * 16 + l15;
  const i32x4* gH = Ph + (((size_t)mblk * 64 + kh * 32) << 9) + g * 128 + m128 + wm * 16 + l15;
  const i32x4* gB = Bq + (((size_t)nb * 64 + kh * 32) << 9) + g * 128 + wn * 64 + l15;

  // fragment prefetch tt=0 (latency overlaps the scale phase)
  i32x4 aS = gS[0], aH = gH[0];
  i32x4 bf[4];
  #pragma unroll
  for (int c = 0; c < 4; c++) bf[c] = gB[c * 16];

  // scales (pre-loop; block_absmax barriers are the only ones before the merge)
  float s1v = block_absmax(part + 512, 512, b1f, 4096, red, &slot) / 127.0f;
  float s2v = block_absmax(part + 1024, 512, b2f, 1024, red, &slot) / 127.0f;
  float mult2 = s1v * s2v / s2v;   // exact f32 expr as reference
  int bq[4];
  #pragma unroll
  for (int c = 0; c < 4; c++)
    bq[c] = (int)rintf(b2f[nb * 128 + wn * 64 + c * 16 + l15] / s2v);

  i32x4 accS[4], accH[4];
  #pragma unroll
  for (int c = 0; c < 4; c++) { accS[c] = (i32x4)(0); accH[c] = (i32x4)(0); }

  #pragma unroll 2
  for (int tt = 0; tt < 32; ++tt) {
    int tn = (tt + 1 < 32) ? (tt + 1) : 31;       // last iter re-reads (harmless)
    const i32x4* pS = gS + (size_t)tn * 512;
    const i32x4* pH = gH + (size_t)tn * 512;
    const i32x4* pB = gB + (size_t)tn * 512;
    i32x4 aSn = pS[0], aHn = pH[0];
    i32x4 bn[4];
    #pragma unroll
    for (int c = 0; c < 4; c++) bn[c] = pB[c * 16];
    #pragma unroll
    for (int c = 0; c < 4; c++) {
      accS[c] = __builtin_amdgcn_mfma_i32_16x16x64_i8(aS, bf[c], accS[c], 0, 0, 0);
      accH[c] = __builtin_amdgcn_mfma_i32_16x16x64_i8(aH, bf[c], accH[c], 0, 0, 0);
    }
    aS = aSn; aH = aHn;
    #pragma unroll
    for (int c = 0; c < 4; c++) bf[c] = bn[c];
  }

  // one-time merge of k-halves via LDS; exact mod 2^32
  if (kh == 1) {
    #pragma unroll
    for (int c = 0; c < 4; c++)
      #pragma unroll
      for (int q = 0; q < 4; q++)
        mg[(wm * 16 + 4 * g + q) * 128 + wn * 64 + c * 16 + l15] =
            accS[c][q] + accH[c][q] * 256;
  }
  __syncthreads();
  if (kh == 0) {
    #pragma unroll
    for (int c = 0; c < 4; c++) {
      int n = nb * 128 + wn * 64 + c * 16 + l15;
      #pragma unroll
      for (int q = 0; q < 4; q++) {
        int rloc = wm * 16 + 4 * g + q;
        int y0 = accS[c][q] + accH[c][q] * 256 + mg[rloc * 128 + wn * 64 + c * 16 + l15];
        int o = (short)((int)rintf((float)y0 * mult2) + bq[c]);   // int16 semantics
        out[(size_t)(mb * 32 + rloc) * 1024 + n] = (float)o * s2v;
      }
    }
  }
}

extern "C" void kernel_launch(void* const* d_in, const int* in_sizes, int n_in,
                              void* d_out, int out_size, void* d_ws, size_t ws_size,
                              hipStream_t stream) {
  const float* x   = (const float*)d_in[0];
  const float* w1f = (const float*)d_in[1];
  const float* b1f = (const float*)d_in[2];
  const float* w2f = (const float*)d_in[3];
  const float* b2f = (const float*)d_in[4];
  float* out = (float*)d_out;

  char* ws = (char*)d_ws;
  float*  part    = (float*)(ws + WS_PART);
  i32x4*  xq      = (i32x4*)(ws + WS_XQ);
  i32x4*  w1qt    = (i32x4*)(ws + WS_W1QT);
  i32x4*  w2qt    = (i32x4*)(ws + WS_W2QT);
  unsigned* ps    = (unsigned*)(ws + WS_PS);
  unsigned* ph    = (unsigned*)(ws + WS_PH);

  k_absmax3<<<1536, 256, 0, stream>>>(x, w1f, w2f, part);
  k_prep<<<3072, 256, 0, stream>>>(x, w1f, w2f, b1f, b2f, part, xq, w1qt, w2qt);
  k_gemm1<<<dim3(32, 32), 256, 0, stream>>>(w1qt, xq, part, b1f, ps, ph);
  k_gemm2<<<1024, 512, 0, stream>>>((const i32x4*)ps, (const i32x4*)ph, w2qt,
                                    part, b1f, b2f, out);
}

// Round 8
// 192.661 us; speedup vs baseline: 1.0603x; 1.0603x over previous
//
#include <hip/hip_runtime.h>
#include <stdint.h>

typedef int   i32x4 __attribute__((ext_vector_type(4)));
typedef float f32x4 __attribute__((ext_vector_type(4)));

// ---------------- workspace layout (bytes) ----------------
#define WS_PART    0                         // 1536 floats: per-block absmax partials
#define WS_XQ      32768                     // 4 MB  int8 swizzled [32][16][4][128][16]
#define WS_W1QT    (WS_XQ   + 4096*1024)     // 4 MB  w1^T swizzled [32][16][4][128][16]
#define WS_W2QT    (WS_W1QT + 4096*1024)     // 4 MB  w2^T swizzled [8][64][4][128][16]
#define WS_PS      (WS_W2QT + 4096*1024)     // 16 MB plane_s swizzled [32][64][4][128][16]
#define WS_PH      (WS_PS   + 4096*4096)     // 16 MB plane_h

__device__ __forceinline__ void async16(const void* g, void* l) {
  __builtin_amdgcn_global_load_lds(
      (const __attribute__((address_space(1))) unsigned*)g,
      (__attribute__((address_space(3))) unsigned*)l, 16, 0, 0);
}

// block-wide absmax over p0[0..n0) and optional p1[0..n1); bit-exact in any order
__device__ __forceinline__ float block_absmax(const float* __restrict__ p0, int n0,
                                              const float* __restrict__ p1, int n1,
                                              float* red, float* slot) {
  int tid = threadIdx.x, nt = blockDim.x;
  float m = 0.f;
  for (int i = tid; i < n0; i += nt) m = fmaxf(m, fabsf(p0[i]));
  if (p1) for (int i = tid; i < n1; i += nt) m = fmaxf(m, fabsf(p1[i]));
  for (int off = 32; off; off >>= 1) m = fmaxf(m, __shfl_down(m, off));
  if ((tid & 63) == 0) red[tid >> 6] = m;
  __syncthreads();
  if (tid == 0) {
    int nw = nt >> 6;
    float M = red[0];
    for (int w = 1; w < nw; w++) M = fmaxf(M, red[w]);
    *slot = M;
  }
  __syncthreads();
  return *slot;
}

// ---------------- abs-max partials over x, w1f, w2f ----------------
__global__ void k_absmax3(const float* __restrict__ x, const float* __restrict__ w1,
                          const float* __restrict__ w2, float* __restrict__ part) {
  int seg = blockIdx.x >> 9;              // 0,1,2
  int b = blockIdx.x & 511;
  const float* p = (seg == 0) ? x : (seg == 1) ? w1 : w2;
  int i = b * 256 + threadIdx.x;
  float m = 0.f;
  #pragma unroll
  for (int it = 0; it < 8; it++) {
    f32x4 v = ((const f32x4*)p)[i + it * 131072];
    m = fmaxf(m, fmaxf(fmaxf(fabsf(v.x), fabsf(v.y)), fmaxf(fabsf(v.z), fabsf(v.w))));
  }
  for (int off = 32; off; off >>= 1) m = fmaxf(m, __shfl_down(m, off));
  __shared__ float red[4];
  if ((threadIdx.x & 63) == 0) red[threadIdx.x >> 6] = m;
  __syncthreads();
  if (threadIdx.x == 0)
    part[blockIdx.x] = fmaxf(fmaxf(red[0], red[1]), fmaxf(red[2], red[3]));
}

// ---------------- quantize + transpose a weight matrix (inline body) ----------------
__device__ __forceinline__ void quantT_body(const float* __restrict__ w, float s,
                                            i32x4* __restrict__ out, int C, int tkbits,
                                            int b) {
  int L = b * 256 + threadIdx.x;
  int h_in = L & 127;
  int kb = (L >> 7) & 3;
  int tk = (L >> 9) & ((1 << tkbits) - 1);
  int hblk = L >> (9 + tkbits);
  int h = hblk * 128 + h_in;
  int k0 = (tk * 4 + kb) * 16;
  int wd[4];
  #pragma unroll
  for (int d = 0; d < 4; d++) {
    unsigned acc = 0;
    #pragma unroll
    for (int j = 0; j < 4; j++) {
      float v = w[(size_t)(k0 + d * 4 + j) * C + h];
      int q = (int)rintf(v / s) & 255;
      acc |= (unsigned)q << (8 * j);
    }
    wd[d] = (int)acc;
  }
  i32x4 o; o.x = wd[0]; o.y = wd[1]; o.z = wd[2]; o.w = wd[3];
  out[L] = o;
}

// ---------------- fused prep: quant_x + quantT(w1) + quantT(w2) ----------------
__global__ void k_prep(const float* __restrict__ x, const float* __restrict__ w1f,
                       const float* __restrict__ w2f, const float* __restrict__ b1f,
                       const float* __restrict__ b2f, const float* __restrict__ part,
                       i32x4* __restrict__ xq, i32x4* __restrict__ w1qt,
                       i32x4* __restrict__ w2qt) {
  __shared__ float red[4];
  __shared__ float slot;
  int seg = blockIdx.x >> 10;             // block-uniform
  int b = blockIdx.x & 1023;
  if (seg == 0) {
    float s = block_absmax(part, 512, nullptr, 0, red, &slot) / 127.0f;
    int L = b * 256 + threadIdx.x;
    int m_in = L & 127, kb = (L >> 7) & 3, tk = (L >> 9) & 15, mblk = L >> 13;
    int m = mblk * 128 + m_in;
    int k0 = (tk * 4 + kb) * 16;
    const f32x4* px = (const f32x4*)(x + m * 1024 + k0);
    int wd[4];
    #pragma unroll
    for (int d = 0; d < 4; d++) {
      f32x4 v = px[d];
      int b0 = (int)rintf(v.x / s) & 255;
      int b1 = (int)rintf(v.y / s) & 255;
      int b2 = (int)rintf(v.z / s) & 255;
      int b3 = (int)rintf(v.w / s) & 255;
      wd[d] = b0 | (b1 << 8) | (b2 << 16) | (b3 << 24);
    }
    i32x4 o; o.x = wd[0]; o.y = wd[1]; o.z = wd[2]; o.w = wd[3];
    xq[L] = o;
  } else if (seg == 1) {
    float s = block_absmax(part + 512, 512, b1f, 4096, red, &slot) / 127.0f;
    quantT_body(w1f, s, w1qt, 4096, 4, b);
  } else {
    float s = block_absmax(part + 1024, 512, b2f, 1024, red, &slot) / 127.0f;
    quantT_body(w2f, s, w2qt, 1024, 6, b);
  }
}

// ---------------- GEMM1: o1^T = w1q^T · x_q^T  (3-stage pipelined LDS) ----------------
// Per iter: barrier -> issue tile t+2 (post-barrier, so each barrier's vmcnt(0)
// drain waits only on loads aged a full iteration -> ~free) -> compute tile t.
__launch_bounds__(256, 3)
__global__ void k_gemm1(const i32x4* __restrict__ Aq, const i32x4* __restrict__ Bq,
                        const float* __restrict__ part, const float* __restrict__ b1f,
                        unsigned* __restrict__ plane_s, unsigned* __restrict__ plane_h) {
  __shared__ i32x4 As[3][512];   // 24 KB: [stage][kb4][row128]
  __shared__ i32x4 Bs[3][512];   // 24 KB
  __shared__ float red[4];
  __shared__ float slot;
  __shared__ int b1s[128];
  int tid = threadIdx.x;
  int bb = blockIdx.x;   // batch block, 0..31
  int hb = blockIdx.y;   // H block,    0..31
  int lane = tid & 63, wid = tid >> 6;
  int wm = wid & 1, wn = wid >> 1;
  int g = lane >> 4, l15 = lane & 15;

  const i32x4* gA = Aq + (size_t)hb * 16 * 512;
  const i32x4* gB = Bq + (size_t)bb * 16 * 512;

  int abase = g * 128 + wm * 64 + l15;
  int bbase = g * 128 + wn * 64 + l15;

  // prologue: stage tiles 0 and 1 (latency overlaps the scale phase)
  #pragma unroll
  for (int p = 0; p < 2; p++) {
    const i32x4* ga = gA + p * 512;
    const i32x4* gb = gB + p * 512;
    async16(ga + tid, &As[p][tid]);
    async16(ga + tid + 256, &As[p][tid + 256]);
    async16(gb + tid, &Bs[p][tid]);
    async16(gb + tid + 256, &Bs[p][tid + 256]);
  }

  // recompute scales from partials (bit-identical across kernels)
  float sx  = block_absmax(part, 512, nullptr, 0, red, &slot) / 127.0f;
  float s1v = block_absmax(part + 512, 512, b1f, 4096, red, &slot) / 127.0f;
  float mult1 = sx * s1v / s1v;   // exact f32 expr as reference
  if (tid < 128) b1s[tid] = (int)rintf(b1f[hb * 128 + tid] / s1v);
  // block_absmax's trailing barrier drained the prologue stages + publishes b1s path

  i32x4 acc[4][4];
  #pragma unroll
  for (int r = 0; r < 4; r++)
    #pragma unroll
    for (int c = 0; c < 4; c++) acc[r][c] = (i32x4)(0);

  int cur = 0, wr = 2;
  for (int t = 0; t < 16; ++t) {
    __syncthreads();                      // stage(t) ready (drained at barrier t-1)
    if (t + 2 < 16) {                     // issue tile t+2 into stage wr
      const i32x4* ga = gA + (t + 2) * 512;
      const i32x4* gb = gB + (t + 2) * 512;
      async16(ga + tid, &As[wr][tid]);
      async16(ga + tid + 256, &As[wr][tid + 256]);
      async16(gb + tid, &Bs[wr][tid]);
      async16(gb + tid + 256, &Bs[wr][tid + 256]);
    }
    i32x4 af[4], bf[4];
    #pragma unroll
    for (int r = 0; r < 4; r++) af[r] = As[cur][abase + r * 16];
    #pragma unroll
    for (int c = 0; c < 4; c++) bf[c] = Bs[cur][bbase + c * 16];
    #pragma unroll
    for (int r = 0; r < 4; r++)
      #pragma unroll
      for (int c = 0; c < 4; c++)
        acc[r][c] = __builtin_amdgcn_mfma_i32_16x16x64_i8(af[r], bf[c], acc[r][c], 0, 0, 0);
    cur = (cur == 2) ? 0 : cur + 1;
    wr  = (wr  == 2) ? 0 : wr  + 1;
  }

  int t2base = hb * 2 + wm;
  #pragma unroll
  for (int r = 0; r < 4; r++) {
    int hloc = wm * 64 + r * 16 + 4 * g;
    int bq0 = b1s[hloc], bq1 = b1s[hloc + 1], bq2 = b1s[hloc + 2], bq3 = b1s[hloc + 3];
    #pragma unroll
    for (int c = 0; c < 4; c++) {
      unsigned lo = 0, hi = 0;
      #pragma unroll
      for (int q = 0; q < 4; q++) {
        int y0 = acc[r][c][q];
        int bqv = (q == 0) ? bq0 : (q == 1) ? bq1 : (q == 2) ? bq2 : bq3;
        int o = (short)((int)rintf((float)y0 * mult1) + bqv);    // int16 semantics
        int a = o > 0 ? o : 0;                                   // relu
        int s8 = (int)(signed char)(a & 0xFF);
        int h8 = (a >> 8) + (s8 < 0 ? 1 : 0);                    // a = 256*h8 + s8
        lo |= (unsigned)(s8 & 0xFF) << (8 * q);
        hi |= (unsigned)(h8 & 0xFF) << (8 * q);
      }
      int m_in = wn * 64 + c * 16 + l15;
      unsigned idx = (((unsigned)(bb * 64 + t2base) * 512u + (unsigned)(r * 128 + m_in)) << 2) + g;
      plane_s[idx] = lo;
      plane_h[idx] = hi;
    }
  }
}

// ---------------- GEMM2: 64x128 tile, 3-stage pipelined LDS, dual-plane -------------
// 512 blocks x 256 thr; waves wm2 x wn2, wave tile 32 rows x 64 cols, acc 64 regs.
// Same loads-after-barrier pipeline as gemm1; no split-K, no merge.
__launch_bounds__(256, 3)
__global__ void k_gemm2(const i32x4* __restrict__ Ps, const i32x4* __restrict__ Ph,
                        const i32x4* __restrict__ Bq, const float* __restrict__ part,
                        const float* __restrict__ b1f, const float* __restrict__ b2f,
                        float* __restrict__ out) {
  __shared__ i32x4 sS[3][256];   // 12 KB: [stage][kb4][row64]
  __shared__ i32x4 sH[3][256];   // 12 KB
  __shared__ i32x4 sB[3][512];   // 24 KB: [stage][kb4][col128]
  __shared__ float red[4];
  __shared__ float slot;
  int tid = threadIdx.x;
  int L = blockIdx.x;
  int mb = ((L & 7) << 3) | ((L >> 3) & 7);   // same mb -> same XCD (A-strip L2 reuse)
  int nb = L >> 6;                             // 0..7
  int mblk = mb >> 1, half = mb & 1;
  int lane = tid & 63, wid = tid >> 6;
  int wm = wid & 1, wn = wid >> 1;
  int g = lane >> 4, l15 = lane & 15;
  int a_idx = (tid >> 6) * 128 + half * 64 + (tid & 63);  // global idx within A t-tile
  int abase = g * 64 + wm * 32 + l15;          // LDS [kb4][row64]
  int bbase = g * 128 + wn * 64 + l15;         // LDS [kb4][col128]

  const i32x4* gS = Ps + ((size_t)mblk * 64 << 9);
  const i32x4* gH = Ph + ((size_t)mblk * 64 << 9);
  const i32x4* gB = Bq + ((size_t)nb * 64 << 9);

  // prologue: stage tiles 0 and 1 (latency overlaps the scale phase)
  #pragma unroll
  for (int p = 0; p < 2; p++) {
    async16(gS + p * 512 + a_idx, &sS[p][tid]);
    async16(gH + p * 512 + a_idx, &sH[p][tid]);
    async16(gB + p * 512 + tid, &sB[p][tid]);
    async16(gB + p * 512 + tid + 256, &sB[p][tid + 256]);
  }

  // scales (overlap tile-0/1 latency); trailing barrier drains the prologue
  float s1v = block_absmax(part + 512, 512, b1f, 4096, red, &slot) / 127.0f;
  float s2v = block_absmax(part + 1024, 512, b2f, 1024, red, &slot) / 127.0f;
  float mult2 = s1v * s2v / s2v;   // exact f32 expr as reference
  int bq[4];
  #pragma unroll
  for (int c = 0; c < 4; c++)
    bq[c] = (int)rintf(b2f[nb * 128 + wn * 64 + c * 16 + l15] / s2v);

  i32x4 accS[2][4], accH[2][4];
  #pragma unroll
  for (int r = 0; r < 2; r++)
    #pragma unroll
    for (int c = 0; c < 4; c++) { accS[r][c] = (i32x4)(0); accH[r][c] = (i32x4)(0); }

  int cur = 0, wr = 2;
  for (int t = 0; t < 64; ++t) {
    __syncthreads();                      // stage(t) ready (drained at barrier t-1)
    if (t + 2 < 64) {                     // issue tile t+2 into stage wr
      const i32x4* pS = gS + (size_t)(t + 2) * 512;
      const i32x4* pH = gH + (size_t)(t + 2) * 512;
      const i32x4* pB = gB + (size_t)(t + 2) * 512;
      async16(pS + a_idx, &sS[wr][tid]);
      async16(pH + a_idx, &sH[wr][tid]);
      async16(pB + tid, &sB[wr][tid]);
      async16(pB + tid + 256, &sB[wr][tid + 256]);
    }
    i32x4 aS[2], aH[2], bf[4];
    #pragma unroll
    for (int r = 0; r < 2; r++) {
      aS[r] = sS[cur][abase + r * 16];
      aH[r] = sH[cur][abase + r * 16];
    }
    #pragma unroll
    for (int c = 0; c < 4; c++) bf[c] = sB[cur][bbase + c * 16];
    #pragma unroll
    for (int r = 0; r < 2; r++)
      #pragma unroll
      for (int c = 0; c < 4; c++) {
        accS[r][c] = __builtin_amdgcn_mfma_i32_16x16x64_i8(aS[r], bf[c], accS[r][c], 0, 0, 0);
        accH[r][c] = __builtin_amdgcn_mfma_i32_16x16x64_i8(aH[r], bf[c], accH[r][c], 0, 0, 0);
      }
    cur = (cur == 2) ? 0 : cur + 1;
    wr  = (wr  == 2) ? 0 : wr  + 1;
  }

  float s2 = s2v;
  #pragma unroll
  for (int r = 0; r < 2; r++) {
    int m0 = mb * 64 + wm * 32 + r * 16 + 4 * g;
    #pragma unroll
    for (int c = 0; c < 4; c++) {
      int n = nb * 128 + wn * 64 + c * 16 + l15;
      #pragma unroll
      for (int q = 0; q < 4; q++) {
        int y0 = accS[r][c][q] + accH[r][c][q] * 256;
        int o = (short)((int)rintf((float)y0 * mult2) + bq[c]);   // int16 semantics
        out[(size_t)(m0 + q) * 1024 + n] = (float)o * s2;
      }
    }
  }
}

extern "C" void kernel_launch(void* const* d_in, const int* in_sizes, int n_in,
                              void* d_out, int out_size, void* d_ws, size_t ws_size,
                              hipStream_t stream) {
  const float* x   = (const float*)d_in[0];
  const float* w1f = (const float*)d_in[1];
  const float* b1f = (const float*)d_in[2];
  const float* w2f = (const float*)d_in[3];
  const float* b2f = (const float*)d_in[4];
  float* out = (float*)d_out;

  char* ws = (char*)d_ws;
  float*  part    = (float*)(ws + WS_PART);
  i32x4*  xq      = (i32x4*)(ws + WS_XQ);
  i32x4*  w1qt    = (i32x4*)(ws + WS_W1QT);
  i32x4*  w2qt    = (i32x4*)(ws + WS_W2QT);
  unsigned* ps    = (unsigned*)(ws + WS_PS);
  unsigned* ph    = (unsigned*)(ws + WS_PH);

  k_absmax3<<<1536, 256, 0, stream>>>(x, w1f, w2f, part);
  k_prep<<<3072, 256, 0, stream>>>(x, w1f, w2f, b1f, b2f, part, xq, w1qt, w2qt);
  k_gemm1<<<dim3(32, 32), 256, 0, stream>>>(w1qt, xq, part, b1f, ps, ph);
  k_gemm2<<<512, 256, 0, stream>>>((const i32x4*)ps, (const i32x4*)ph, w2qt,
                                   part, b1f, b2f, out);
}